// Round 3
// baseline (488.438 us; speedup 1.0000x reference)
//
#include <hip/hip_runtime.h>

typedef __attribute__((ext_vector_type(8))) short short8;
typedef __attribute__((ext_vector_type(4))) float f32x4;
typedef unsigned short u16;
typedef unsigned int u32;

#define B_ 8
#define C_ 128
#define D_ 64
#define H_ 32
#define W_ 32
#define CNT_PER_C (B_*D_*H_*W_)   // 524288

// workspace offsets (bytes)
#define WS_PART  0          // 1024*2 f32 = 8192
#define WS_SCALE 8192       // 128 f32
#define WS_SHIFT 8704       // 128 f32
#define WS_WKQV  9216       // 192*128 bf16 = 49152
#define WS_WO    58368      // 128*64 bf16 = 16384
#define WS_OUTP  131072     // 8192 * 8192 bf16 = 134217728

__device__ __forceinline__ u16 f2bf(float f){
  u32 u = __builtin_bit_cast(u32, f);
  u32 r = u + 0x7FFFu + ((u >> 16) & 1u);
  return (u16)(r >> 16);
}
__device__ __forceinline__ float bf2f(u16 h){
  u32 u = ((u32)h) << 16;
  return __builtin_bit_cast(float, u);
}

#define SWZ(colbyte, row) ((colbyte) ^ (((row)&7)<<4))

// ---------------- K0: weights -> bf16 ----------------
__global__ void k_prep(const float* wk, const float* wq, const float* wv,
                       const float* wo, u16* wkqv_bf, u16* wo_bf){
  int idx = blockIdx.x*1024 + threadIdx.x*4;
#pragma unroll
  for (int i=0;i<4;i++){
    int id = idx+i;
    if (id < 24576){
      int r = id >> 7, c = id & 127;
      float v = (r<64) ? wk[r*128+c] : (r<128) ? wq[(r-64)*128+c] : wv[(r-128)*128+c];
      wkqv_bf[id] = f2bf(v);
    } else {
      int j = id - 24576;
      wo_bf[j] = f2bf(wo[j]);
    }
  }
}

// ---------------- K1a: per-(c,b) partial sums ----------------
__global__ __launch_bounds__(256) void k_stats1(const float* x, float* part){
  int cb = blockIdx.x; int c = cb>>3, b = cb&7;
  const float4* p = (const float4*)(x + ((size_t)(b*C_ + c))*65536);
  int t = threadIdx.x;
  float s=0.f, s2=0.f;
  for (int i=0;i<64;i++){
    float4 v = p[t + i*256];
    s  += v.x+v.y+v.z+v.w;
    s2 += v.x*v.x + v.y*v.y + v.z*v.z + v.w*v.w;
  }
  for (int off=32; off; off>>=1){ s += __shfl_down(s, off, 64); s2 += __shfl_down(s2, off, 64); }
  __shared__ float ls[8];
  int wid = t>>6, lane = t&63;
  if (lane==0){ ls[wid*2]=s; ls[wid*2+1]=s2; }
  __syncthreads();
  if (t==0){
    float S=0.f, S2=0.f;
    for (int wv=0; wv<4; wv++){ S+=ls[wv*2]; S2+=ls[wv*2+1]; }
    part[cb*2]=S; part[cb*2+1]=S2;
  }
}

// ---------------- K1b: finalize scale/shift ----------------
__global__ void k_stats2(const float* part, const float* gamma, const float* beta,
                         float* scale, float* shift){
  int c = threadIdx.x;
  float S=0.f, S2=0.f;
  for (int b=0;b<8;b++){ S += part[(c*8+b)*2]; S2 += part[(c*8+b)*2+1]; }
  float inv = 1.0f/(float)CNT_PER_C;
  float mean = S*inv;
  float var  = S2*inv - mean*mean;
  float rstd = rsqrtf(var + 1e-5f);
  float sc = gamma[c]*rstd;
  scale[c] = sc; shift[c] = beta[c] - mean*sc;
}

// ---------------- K2: normalize + transpose -> xn_t[n][d][c] bf16 ----------------
__global__ __launch_bounds__(256) void k_norm_t(const float* x, const float* scale,
                                                const float* shift, u16* xn_t){
  __shared__ u16 lt[8*32*72];
  __shared__ float lsc[128], lsh[128];
  int t = threadIdx.x;
  if (t < 128){ lsc[t] = scale[t]; lsh[t] = shift[t]; }
  int bid = blockIdx.x;
  int bh = bid>>3, dq = bid&7;
  int b = bh>>5, h = bh&31;
  int d0 = dq*8;
  int n0 = bh*32;
  __syncthreads();
  int w = t&31, p = t>>5;     // load mapping
  int cb = t&7, w2 = t>>3;    // store mapping
  for (int c0=0; c0<128; c0+=64){
    for (int r=0;r<64;r++){
      int pi = r*8+p; int c = pi>>3, d = pi&7;
      int cg = c0+c;
      size_t gi = ((size_t)((b*C_+cg)*D_ + d0+d))*1024 + h*32 + w;
      float v = x[gi]*lsc[cg] + lsh[cg];
      lt[(d*32+w)*72 + c] = f2bf(v);
    }
    __syncthreads();
#pragma unroll
    for (int d=0; d<8; d++){
      uint4 v = *(const uint4*)&lt[(d*32+w2)*72 + cb*8];
      size_t go = ((size_t)(n0+w2))*8192 + (size_t)(d0+d)*128 + c0 + cb*8;
      *(uint4*)(&xn_t[go]) = v;
    }
    __syncthreads();
  }
}

// ---------------- K3: per-sequence fused attention ----------------
// LDS: 0: xn [64][128] bf16 (reused as scores_t f32 [64][64]); 16384: kt[64][64];
//      24576: qt; 32768: v; 40960: a_t; 49152: attn_t  (all bf16, XOR-swizzled rows)
__global__ __launch_bounds__(256) void k_attn(const u16* xn_t, const u16* wkqv,
                                              const u16* wo, u16* out_pre){
  __shared__ alignas(16) unsigned char sm[57344];
  int t = threadIdx.x, lane = t&63, wid = t>>6;
  int lr = lane&15, lk = lane>>4;
  int n = blockIdx.x;
  const u16* xg = xn_t + (size_t)n*8192;

  // stage xn (swizzled)
#pragma unroll
  for (int r=0;r<4;r++){
    int blk = r*256 + t;
    int d = blk>>4, cbk = blk&15;
    uint4 v = *(const uint4*)(xg + blk*8);
    *(uint4*)(sm + d*256 + SWZ(cbk*16, d)) = v;
  }
  __syncthreads();

  // ---- GEMM1: KQV[192,64] = Wkqv[192,128] x xn[128,64] ----
  short8 bfr[4][4];
#pragma unroll
  for (int ct=0; ct<4; ct++)
#pragma unroll
    for (int ks=0; ks<4; ks++){
      int d = ct*16 + lr;
      bfr[ct][ks] = *(const short8*)(sm + d*256 + SWZ((ks*32+lk*8)*2, d));
    }
  f32x4 acc[3][4];
#pragma unroll
  for (int i=0;i<3;i++)
#pragma unroll
    for (int ct=0;ct<4;ct++) acc[i][ct] = (f32x4){0.f,0.f,0.f,0.f};
  for (int i=0;i<3;i++){
    int rt = wid*3+i;
    short8 af[4];
#pragma unroll
    for (int ks=0;ks<4;ks++)
      af[ks] = *(const short8*)(wkqv + (size_t)(rt*16+lr)*128 + ks*32 + lk*8);
#pragma unroll
    for (int ct=0;ct<4;ct++)
#pragma unroll
      for (int ks=0;ks<4;ks++)
        acc[i][ct] = __builtin_amdgcn_mfma_f32_16x16x32_bf16(af[ks], bfr[ct][ks], acc[i][ct], 0,0,0);
  }
  // scatter K->kt[i][s], Q->qt[j][s], V->v[s][i]
  for (int i=0;i<3;i++){
    int rt = wid*3+i;
#pragma unroll
    for (int ct=0;ct<4;ct++){
#pragma unroll
      for (int e=0;e<4;e++){
        int R = rt*16 + lk*4 + e;
        int Dd = ct*16 + lr;
        u16 hv = f2bf(acc[i][ct][e]);
        if (R < 64)       *(u16*)(sm + 16384 + Dd*128 + SWZ(R*2, Dd)) = hv;
        else if (R < 128) *(u16*)(sm + 24576 + Dd*128 + SWZ((R-64)*2, Dd)) = hv;
        else              *(u16*)(sm + 32768 + (R-128)*128 + SWZ(Dd*2, R-128)) = hv;
      }
    }
  }
  __syncthreads();

  // ---- GEMM2: scores_t[j][i] = sum_s Q[s,j] K[s,i], scaled 1/8 ----
  {
    f32x4 sacc[4];
#pragma unroll
    for (int it=0;it<4;it++) sacc[it] = (f32x4){0.f,0.f,0.f,0.f};
    short8 aq[2];
#pragma unroll
    for (int ks=0;ks<2;ks++){
      int j = wid*16 + lr;
      aq[ks] = *(const short8*)(sm + 24576 + j*128 + SWZ((ks*32+lk*8)*2, j));
    }
#pragma unroll
    for (int it=0; it<4; it++)
#pragma unroll
      for (int ks=0;ks<2;ks++){
        int ii = it*16 + lr;
        short8 bk = *(const short8*)(sm + 16384 + ii*128 + SWZ((ks*32+lk*8)*2, ii));
        sacc[it] = __builtin_amdgcn_mfma_f32_16x16x32_bf16(aq[ks], bk, sacc[it], 0,0,0);
      }
#pragma unroll
    for (int it=0;it<4;it++)
#pragma unroll
      for (int e=0;e<4;e++){
        int J = wid*16 + lk*4 + e;
        int I = it*16 + lr;
        *(float*)(sm + J*256 + SWZ(I*4, J)) = sacc[it][e]*0.125f;
      }
  }
  __syncthreads();

  // ---- softmax over i (contiguous in scores_t rows) -> a_t[j][i] bf16 ----
  {
    int j = t>>2, q = t&3;
    f32x4 vv[4];
    float m = -1e30f;
#pragma unroll
    for (int bi=0;bi<4;bi++){
      int ib = q*4+bi;
      vv[bi] = *(const f32x4*)(sm + j*256 + SWZ(ib*16, j));
      m = fmaxf(m, fmaxf(fmaxf(vv[bi][0],vv[bi][1]), fmaxf(vv[bi][2],vv[bi][3])));
    }
    m = fmaxf(m, __shfl_xor(m, 1, 64));
    m = fmaxf(m, __shfl_xor(m, 2, 64));
    float ssum = 0.f;
#pragma unroll
    for (int bi=0;bi<4;bi++)
#pragma unroll
      for (int e=0;e<4;e++){ vv[bi][e] = __expf(vv[bi][e]-m); ssum += vv[bi][e]; }
    ssum += __shfl_xor(ssum, 1, 64);
    ssum += __shfl_xor(ssum, 2, 64);
    float inv = 1.0f/ssum;
#pragma unroll
    for (int bi=0;bi<4;bi++){
      int ib = q*4+bi;
      ushort4 h;
      h.x = f2bf(vv[bi][0]*inv); h.y = f2bf(vv[bi][1]*inv);
      h.z = f2bf(vv[bi][2]*inv); h.w = f2bf(vv[bi][3]*inv);
      *(ushort4*)(sm + 40960 + j*128 + SWZ(ib*8, j)) = h;
    }
  }
  __syncthreads();

  // ---- GEMM3: attn[s,j] = sum_i V[s,i] a[i,j] -> attn_t[j][s] ----
  {
    f32x4 aacc[4];
#pragma unroll
    for (int jt=0;jt<4;jt++) aacc[jt] = (f32x4){0.f,0.f,0.f,0.f};
    short8 av[2];
#pragma unroll
    for (int ks=0;ks<2;ks++){
      int s = wid*16 + lr;
      av[ks] = *(const short8*)(sm + 32768 + s*128 + SWZ((ks*32+lk*8)*2, s));
    }
#pragma unroll
    for (int jt=0;jt<4;jt++)
#pragma unroll
      for (int ks=0;ks<2;ks++){
        int j = jt*16 + lr;
        short8 ba = *(const short8*)(sm + 40960 + j*128 + SWZ((ks*32+lk*8)*2, j));
        aacc[jt] = __builtin_amdgcn_mfma_f32_16x16x32_bf16(av[ks], ba, aacc[jt], 0,0,0);
      }
#pragma unroll
    for (int jt=0;jt<4;jt++)
#pragma unroll
      for (int e=0;e<4;e++){
        int Sr = wid*16 + lk*4 + e;
        int J = jt*16 + lr;
        *(u16*)(sm + 49152 + J*128 + SWZ(Sr*2, J)) = f2bf(aacc[jt][e]);
      }
  }
  __syncthreads();

  // ---- GEMM4: out_pre[c,d] = sum_s Wo[c,s] attn[s,d] ----
  {
    short8 batt[4][2];
#pragma unroll
    for (int dt=0;dt<4;dt++)
#pragma unroll
      for (int ks=0;ks<2;ks++){
        int d = dt*16 + lr;
        batt[dt][ks] = *(const short8*)(sm + 49152 + d*128 + SWZ((ks*32+lk*8)*2, d));
      }
    u16* og = out_pre + (size_t)n*8192;
#pragma unroll
    for (int cti=0;cti<2;cti++){
      int ct = wid*2+cti;
      short8 aw[2];
#pragma unroll
      for (int ks=0;ks<2;ks++)
        aw[ks] = *(const short8*)(wo + (size_t)(ct*16+lr)*64 + ks*32 + lk*8);
      f32x4 oacc[4];
#pragma unroll
      for (int dt=0;dt<4;dt++) oacc[dt] = (f32x4){0.f,0.f,0.f,0.f};
#pragma unroll
      for (int dt=0;dt<4;dt++)
#pragma unroll
        for (int ks=0;ks<2;ks++)
          oacc[dt] = __builtin_amdgcn_mfma_f32_16x16x32_bf16(aw[ks], batt[dt][ks], oacc[dt], 0,0,0);
#pragma unroll
      for (int dt=0;dt<4;dt++)
#pragma unroll
        for (int e=0;e<4;e++){
          int Cc = ct*16 + lk*4 + e;
          int Dd = dt*16 + lr;
          og[Cc*64 + Dd] = f2bf(oacc[dt][e]);
        }
    }
  }
}

// ---------------- K4: out = x + untranspose(out_pre) ----------------
__global__ __launch_bounds__(256) void k_merge(const float* x, const u16* out_pre, float* out){
  __shared__ u16 lt[8*32*72];
  int t = threadIdx.x;
  int bid = blockIdx.x;
  int bh = bid>>2, cq = bid&3;
  int b = bh>>5, h = bh&31;
  int n0 = bh*32;
  int db = t&7, rid = t>>3;  // read mapping (rid = w)
  int w = t&31, rr = t>>5;   // write mapping
  for (int cc=0; cc<4; cc++){
    int cbase = cq*32 + cc*8;
#pragma unroll
    for (int ci=0; ci<8; ci++){
      uint4 v = *(const uint4*)(out_pre + ((size_t)(n0+rid))*8192 + (cbase+ci)*64 + db*8);
      *(uint4*)&lt[(ci*32+rid)*72 + db*8] = v;
    }
    __syncthreads();
    for (int rp=0; rp<64; rp++){
      int pp = rp*8 + rr;
      int ci = pp>>6, d = pp&63;
      float v = bf2f(lt[(ci*32+w)*72 + d]);
      size_t gi = ((size_t)((b*C_+cbase+ci)*D_ + d))*1024 + h*32 + w;
      out[gi] = x[gi] + v;
    }
    __syncthreads();
  }
}

extern "C" void kernel_launch(void* const* d_in, const int* in_sizes, int n_in,
                              void* d_out, int out_size, void* d_ws, size_t ws_size,
                              hipStream_t stream){
  const float* x     = (const float*)d_in[0];
  const float* Wk    = (const float*)d_in[1];
  const float* Wq    = (const float*)d_in[2];
  const float* Wv    = (const float*)d_in[3];
  const float* Wo    = (const float*)d_in[4];
  const float* gamma = (const float*)d_in[5];
  const float* beta  = (const float*)d_in[6];
  float* out = (float*)d_out;
  char* ws = (char*)d_ws;

  float* part  = (float*)(ws + WS_PART);
  float* scale = (float*)(ws + WS_SCALE);
  float* shift = (float*)(ws + WS_SHIFT);
  u16* wkqv = (u16*)(ws + WS_WKQV);
  u16* wo_bf = (u16*)(ws + WS_WO);
  u16* outp = (u16*)(ws + WS_OUTP);
  u16* xn_t = (u16*)d_out;   // lower 134MB of d_out used as scratch; dead before k_merge writes

  k_prep  <<<32,   256, 0, stream>>>(Wk, Wq, Wv, Wo, wkqv, wo_bf);
  k_stats1<<<1024, 256, 0, stream>>>(x, part);
  k_stats2<<<1,    128, 0, stream>>>(part, gamma, beta, scale, shift);
  k_norm_t<<<2048, 256, 0, stream>>>(x, scale, shift, xn_t);
  k_attn  <<<8192, 256, 0, stream>>>(xn_t, wkqv, wo_bf, outp);
  k_merge <<<1024, 256, 0, stream>>>(x, outp, out);
}

// Round 4
// 435.061 us; speedup vs baseline: 1.1227x; 1.1227x over previous
//
#include <hip/hip_runtime.h>

typedef __attribute__((ext_vector_type(8))) short short8;
typedef __attribute__((ext_vector_type(4))) float f32x4;
typedef unsigned short u16;
typedef unsigned int u32;

#define B_ 8
#define C_ 128
#define D_ 64
#define H_ 32
#define W_ 32
#define CNT_PER_C (B_*D_*H_*W_)   // 524288

// workspace offsets (bytes)
#define WS_PART  0          // 1024*2 f32 = 8192
#define WS_SCALE 8192       // 128 f32
#define WS_SHIFT 8704       // 128 f32
#define WS_WKQV  9216       // 192*128 bf16 = 49152
#define WS_WO    58368      // 128*64 bf16 = 16384
#define WS_OUTP  131072     // 8192 * 8192 bf16 = 134217728

__device__ __forceinline__ u16 f2bf(float f){
  u32 u = __builtin_bit_cast(u32, f);
  u32 r = u + 0x7FFFu + ((u >> 16) & 1u);
  return (u16)(r >> 16);
}
__device__ __forceinline__ float bf2f(u16 h){
  u32 u = ((u32)h) << 16;
  return __builtin_bit_cast(float, u);
}

#define SWZ(colbyte, row) ((colbyte) ^ (((row)&7)<<4))

// ---------------- K0: weights -> bf16 ----------------
__global__ void k_prep(const float* wk, const float* wq, const float* wv,
                       const float* wo, u16* wkqv_bf, u16* wo_bf){
  int idx = blockIdx.x*1024 + threadIdx.x*4;
#pragma unroll
  for (int i=0;i<4;i++){
    int id = idx+i;
    if (id < 24576){
      int r = id >> 7, c = id & 127;
      float v = (r<64) ? wk[r*128+c] : (r<128) ? wq[(r-64)*128+c] : wv[(r-128)*128+c];
      wkqv_bf[id] = f2bf(v);
    } else {
      int j = id - 24576;
      wo_bf[j] = f2bf(wo[j]);
    }
  }
}

// ---------------- K1a: per-(c,b) partial sums ----------------
__global__ __launch_bounds__(256) void k_stats1(const float* x, float* part){
  int cb = blockIdx.x; int c = cb>>3, b = cb&7;
  const float4* p = (const float4*)(x + ((size_t)(b*C_ + c))*65536);
  int t = threadIdx.x;
  float s=0.f, s2=0.f;
  for (int i=0;i<64;i++){
    float4 v = p[t + i*256];
    s  += v.x+v.y+v.z+v.w;
    s2 += v.x*v.x + v.y*v.y + v.z*v.z + v.w*v.w;
  }
  for (int off=32; off; off>>=1){ s += __shfl_down(s, off, 64); s2 += __shfl_down(s2, off, 64); }
  __shared__ float ls[8];
  int wid = t>>6, lane = t&63;
  if (lane==0){ ls[wid*2]=s; ls[wid*2+1]=s2; }
  __syncthreads();
  if (t==0){
    float S=0.f, S2=0.f;
    for (int wv=0; wv<4; wv++){ S+=ls[wv*2]; S2+=ls[wv*2+1]; }
    part[cb*2]=S; part[cb*2+1]=S2;
  }
}

// ---------------- K1b: finalize scale/shift ----------------
__global__ void k_stats2(const float* part, const float* gamma, const float* beta,
                         float* scale, float* shift){
  int c = threadIdx.x;
  float S=0.f, S2=0.f;
  for (int b=0;b<8;b++){ S += part[(c*8+b)*2]; S2 += part[(c*8+b)*2+1]; }
  float inv = 1.0f/(float)CNT_PER_C;
  float mean = S*inv;
  float var  = S2*inv - mean*mean;
  float rstd = rsqrtf(var + 1e-5f);
  float sc = gamma[c]*rstd;
  scale[c] = sc; shift[c] = beta[c] - mean*sc;
}

// ---------------- K2: normalize + transpose -> xn_t[n][d][c] bf16 ----------------
// LDS layout lm[w][rowpos ^ (w&28)], rowpos = dd*64 + cl (per c-half).
// Load: float4 x reads (4 w's, one (c,dd) row) -> 4 scalar b16 LDS stores (<=2-way).
// Write: ds_read_b128 (8 c's for fixed (n,dd), internally half-swapped when n&4)
//        -> uint4 global stores. Both global phases: 8x128B segments / wave-instr.
__global__ __launch_bounds__(256) void k_norm_t(const float* x, const float* scale,
                                                const float* shift, u16* xn_t){
  __shared__ u16 lm[32*512];           // 32 KB
  __shared__ float lsc[128], lsh[128];
  int t = threadIdx.x;
  if (t < 128){ lsc[t] = scale[t]; lsh[t] = shift[t]; }
  int bid = blockIdx.x;
  int bh = bid>>3, dq = bid&7;
  int b = bh>>5, h = bh&31;
  int d0 = dq*8, n0 = bh*32;
  int s = t>>3, q = t&7;
  __syncthreads();
  for (int h2=0; h2<2; h2++){
    int w4 = q*4;
#pragma unroll
    for (int i=0;i<16;i++){
      int rowpos = i*32 + s;
      int cl = rowpos & 63, dd = rowpos >> 6;
      int c = h2*64 + cl;
      float4 v = *(const float4*)(x + ((size_t)((b*C_ + c)*D_ + d0 + dd))*1024 + h*32 + w4);
      float sc = lsc[c], sh = lsh[c];
      lm[(w4+0)*512 + (rowpos ^ ((w4+0)&28))] = f2bf(v.x*sc + sh);
      lm[(w4+1)*512 + (rowpos ^ ((w4+1)&28))] = f2bf(v.y*sc + sh);
      lm[(w4+2)*512 + (rowpos ^ ((w4+2)&28))] = f2bf(v.z*sc + sh);
      lm[(w4+3)*512 + (rowpos ^ ((w4+3)&28))] = f2bf(v.w*sc + sh);
    }
    __syncthreads();
    {
      int n = s, oct = q;
      int oq = oct ^ ((n>>3)&3);
      bool swp = (n & 4) != 0;
#pragma unroll
      for (int m=0;m<8;m++){
        uint4 raw = *(const uint4*)&lm[n*512 + m*64 + oq*8];
        if (swp){ u32 tx=raw.x, ty=raw.y; raw.x=raw.z; raw.y=raw.w; raw.z=tx; raw.w=ty; }
        *(uint4*)(xn_t + (size_t)(n0+n)*8192 + (size_t)(d0+m)*128 + h2*64 + oct*8) = raw;
      }
    }
    __syncthreads();
  }
}

// ---------------- K3: per-sequence fused attention ----------------
__global__ __launch_bounds__(256) void k_attn(const u16* xn_t, const u16* wkqv,
                                              const u16* wo, u16* out_pre){
  __shared__ alignas(16) unsigned char sm[57344];
  int t = threadIdx.x, lane = t&63, wid = t>>6;
  int lr = lane&15, lk = lane>>4;
  int n = blockIdx.x;
  const u16* xg = xn_t + (size_t)n*8192;

  // stage xn (swizzled)
#pragma unroll
  for (int r=0;r<4;r++){
    int blk = r*256 + t;
    int d = blk>>4, cbk = blk&15;
    uint4 v = *(const uint4*)(xg + blk*8);
    *(uint4*)(sm + d*256 + SWZ(cbk*16, d)) = v;
  }
  __syncthreads();

  // ---- GEMM1: KQV[192,64] = Wkqv[192,128] x xn[128,64] ----
  short8 bfr[4][4];
#pragma unroll
  for (int ct=0; ct<4; ct++)
#pragma unroll
    for (int ks=0; ks<4; ks++){
      int d = ct*16 + lr;
      bfr[ct][ks] = *(const short8*)(sm + d*256 + SWZ((ks*32+lk*8)*2, d));
    }
  f32x4 acc[3][4];
#pragma unroll
  for (int i=0;i<3;i++)
#pragma unroll
    for (int ct=0;ct<4;ct++) acc[i][ct] = (f32x4){0.f,0.f,0.f,0.f};
  for (int i=0;i<3;i++){
    int rt = wid*3+i;
    short8 af[4];
#pragma unroll
    for (int ks=0;ks<4;ks++)
      af[ks] = *(const short8*)(wkqv + (size_t)(rt*16+lr)*128 + ks*32 + lk*8);
#pragma unroll
    for (int ct=0;ct<4;ct++)
#pragma unroll
      for (int ks=0;ks<4;ks++)
        acc[i][ct] = __builtin_amdgcn_mfma_f32_16x16x32_bf16(af[ks], bfr[ct][ks], acc[i][ct], 0,0,0);
  }
  // scatter K->kt[i][s], Q->qt[j][s], V->v[s][i]
  for (int i=0;i<3;i++){
    int rt = wid*3+i;
#pragma unroll
    for (int ct=0;ct<4;ct++){
#pragma unroll
      for (int e=0;e<4;e++){
        int R = rt*16 + lk*4 + e;
        int Dd = ct*16 + lr;
        u16 hv = f2bf(acc[i][ct][e]);
        if (R < 64)       *(u16*)(sm + 16384 + Dd*128 + SWZ(R*2, Dd)) = hv;
        else if (R < 128) *(u16*)(sm + 24576 + Dd*128 + SWZ((R-64)*2, Dd)) = hv;
        else              *(u16*)(sm + 32768 + (R-128)*128 + SWZ(Dd*2, R-128)) = hv;
      }
    }
  }
  __syncthreads();

  // ---- GEMM2: scores_t[j][i] = sum_s Q[s,j] K[s,i], scaled 1/8 ----
  {
    f32x4 sacc[4];
#pragma unroll
    for (int it=0;it<4;it++) sacc[it] = (f32x4){0.f,0.f,0.f,0.f};
    short8 aq[2];
#pragma unroll
    for (int ks=0;ks<2;ks++){
      int j = wid*16 + lr;
      aq[ks] = *(const short8*)(sm + 24576 + j*128 + SWZ((ks*32+lk*8)*2, j));
    }
#pragma unroll
    for (int it=0; it<4; it++)
#pragma unroll
      for (int ks=0;ks<2;ks++){
        int ii = it*16 + lr;
        short8 bk = *(const short8*)(sm + 16384 + ii*128 + SWZ((ks*32+lk*8)*2, ii));
        sacc[it] = __builtin_amdgcn_mfma_f32_16x16x32_bf16(aq[ks], bk, sacc[it], 0,0,0);
      }
#pragma unroll
    for (int it=0;it<4;it++)
#pragma unroll
      for (int e=0;e<4;e++){
        int J = wid*16 + lk*4 + e;
        int I = it*16 + lr;
        *(float*)(sm + J*256 + SWZ(I*4, J)) = sacc[it][e]*0.125f;
      }
  }
  __syncthreads();

  // ---- softmax over i (contiguous in scores_t rows) -> a_t[j][i] bf16 ----
  {
    int j = t>>2, q = t&3;
    f32x4 vv[4];
    float m = -1e30f;
#pragma unroll
    for (int bi=0;bi<4;bi++){
      int ib = q*4+bi;
      vv[bi] = *(const f32x4*)(sm + j*256 + SWZ(ib*16, j));
      m = fmaxf(m, fmaxf(fmaxf(vv[bi][0],vv[bi][1]), fmaxf(vv[bi][2],vv[bi][3])));
    }
    m = fmaxf(m, __shfl_xor(m, 1, 64));
    m = fmaxf(m, __shfl_xor(m, 2, 64));
    float ssum = 0.f;
#pragma unroll
    for (int bi=0;bi<4;bi++)
#pragma unroll
      for (int e=0;e<4;e++){ vv[bi][e] = __expf(vv[bi][e]-m); ssum += vv[bi][e]; }
    ssum += __shfl_xor(ssum, 1, 64);
    ssum += __shfl_xor(ssum, 2, 64);
    float inv = 1.0f/ssum;
#pragma unroll
    for (int bi=0;bi<4;bi++){
      int ib = q*4+bi;
      ushort4 h;
      h.x = f2bf(vv[bi][0]*inv); h.y = f2bf(vv[bi][1]*inv);
      h.z = f2bf(vv[bi][2]*inv); h.w = f2bf(vv[bi][3]*inv);
      *(ushort4*)(sm + 40960 + j*128 + SWZ(ib*8, j)) = h;
    }
  }
  __syncthreads();

  // ---- GEMM3: attn[s,j] = sum_i V[s,i] a[i,j] -> attn_t[j][s] ----
  {
    f32x4 aacc[4];
#pragma unroll
    for (int jt=0;jt<4;jt++) aacc[jt] = (f32x4){0.f,0.f,0.f,0.f};
    short8 av[2];
#pragma unroll
    for (int ks=0;ks<2;ks++){
      int s = wid*16 + lr;
      av[ks] = *(const short8*)(sm + 32768 + s*128 + SWZ((ks*32+lk*8)*2, s));
    }
#pragma unroll
    for (int jt=0;jt<4;jt++)
#pragma unroll
      for (int ks=0;ks<2;ks++){
        int j = jt*16 + lr;
        short8 ba = *(const short8*)(sm + 40960 + j*128 + SWZ((ks*32+lk*8)*2, j));
        aacc[jt] = __builtin_amdgcn_mfma_f32_16x16x32_bf16(av[ks], ba, aacc[jt], 0,0,0);
      }
#pragma unroll
    for (int jt=0;jt<4;jt++)
#pragma unroll
      for (int e=0;e<4;e++){
        int Sr = wid*16 + lk*4 + e;
        int J = jt*16 + lr;
        *(u16*)(sm + 49152 + J*128 + SWZ(Sr*2, J)) = f2bf(aacc[jt][e]);
      }
  }
  __syncthreads();

  // ---- GEMM4: out_pre[c,d] = sum_s Wo[c,s] attn[s,d] ----
  {
    short8 batt[4][2];
#pragma unroll
    for (int dt=0;dt<4;dt++)
#pragma unroll
      for (int ks=0;ks<2;ks++){
        int d = dt*16 + lr;
        batt[dt][ks] = *(const short8*)(sm + 49152 + d*128 + SWZ((ks*32+lk*8)*2, d));
      }
    u16* og = out_pre + (size_t)n*8192;
#pragma unroll
    for (int cti=0;cti<2;cti++){
      int ct = wid*2+cti;
      short8 aw[2];
#pragma unroll
      for (int ks=0;ks<2;ks++)
        aw[ks] = *(const short8*)(wo + (size_t)(ct*16+lr)*64 + ks*32 + lk*8);
      f32x4 oacc[4];
#pragma unroll
      for (int dt=0;dt<4;dt++) oacc[dt] = (f32x4){0.f,0.f,0.f,0.f};
#pragma unroll
      for (int dt=0;dt<4;dt++)
#pragma unroll
        for (int ks=0;ks<2;ks++)
          oacc[dt] = __builtin_amdgcn_mfma_f32_16x16x32_bf16(aw[ks], batt[dt][ks], oacc[dt], 0,0,0);
#pragma unroll
      for (int dt=0;dt<4;dt++)
#pragma unroll
        for (int e=0;e<4;e++){
          int Cc = ct*16 + lk*4 + e;
          int Dd = dt*16 + lr;
          og[Cc*64 + Dd] = f2bf(oacc[dt][e]);
        }
    }
  }
}

// ---------------- K4: out = x + untranspose(out_pre) ----------------
// LDS lm[w][rowpos ^ (w&28)], rowpos = ci*64 + d (8 channels per pass).
// Load: uint4 out_pre reads (8 d's, fixed n) -> ds_write_b128 (half-swapped if n&4).
// Write: 4 scalar b16 LDS reads (<=2-way) -> float4 x read + float4 out store.
__global__ __launch_bounds__(256) void k_merge(const float* x, const u16* out_pre, float* out){
  __shared__ u16 lm[32*512];   // 32 KB
  int t = threadIdx.x;
  int bid = blockIdx.x;
  int bh = bid>>2, cq = bid&3;
  int b = bh>>5, h = bh&31;
  int n0 = bh*32;
  int cbase = cq*32;
  int s = t>>3, q = t&7;
  for (int cc=0; cc<4; cc++){
    int cb = cbase + cc*8;
    // load phase: n = s (0..31), q = d-oct
    {
      int n = s;
      int oq = q ^ ((n>>3)&3);
      bool swp = (n & 4) != 0;
#pragma unroll
      for (int i=0;i<8;i++){
        uint4 raw = *(const uint4*)(out_pre + (size_t)(n0+n)*8192 + (cb+i)*64 + q*8);
        if (swp){ u32 tx=raw.x, ty=raw.y; raw.x=raw.z; raw.y=raw.w; raw.z=tx; raw.w=ty; }
        *(uint4*)&lm[n*512 + i*64 + oq*8] = raw;
      }
    }
    __syncthreads();
    // write phase: row = g*32 + s over (ci,d); w4 = q*4
    {
      int w4 = q*4;
#pragma unroll
      for (int g=0; g<16; g++){
        int row = g*32 + s;
        int ci = row>>6, d = row&63;
        size_t gi = ((size_t)((b*C_ + cb + ci)*D_ + d))*1024 + h*32 + w4;
        float4 xv = *(const float4*)(x + gi);
        float4 ov;
        ov.x = xv.x + bf2f(lm[(w4+0)*512 + (row ^ ((w4+0)&28))]);
        ov.y = xv.y + bf2f(lm[(w4+1)*512 + (row ^ ((w4+1)&28))]);
        ov.z = xv.z + bf2f(lm[(w4+2)*512 + (row ^ ((w4+2)&28))]);
        ov.w = xv.w + bf2f(lm[(w4+3)*512 + (row ^ ((w4+3)&28))]);
        *(float4*)(out + gi) = ov;
      }
    }
    __syncthreads();
  }
}

extern "C" void kernel_launch(void* const* d_in, const int* in_sizes, int n_in,
                              void* d_out, int out_size, void* d_ws, size_t ws_size,
                              hipStream_t stream){
  const float* x     = (const float*)d_in[0];
  const float* Wk    = (const float*)d_in[1];
  const float* Wq    = (const float*)d_in[2];
  const float* Wv    = (const float*)d_in[3];
  const float* Wo    = (const float*)d_in[4];
  const float* gamma = (const float*)d_in[5];
  const float* beta  = (const float*)d_in[6];
  float* out = (float*)d_out;
  char* ws = (char*)d_ws;

  float* part  = (float*)(ws + WS_PART);
  float* scale = (float*)(ws + WS_SCALE);
  float* shift = (float*)(ws + WS_SHIFT);
  u16* wkqv = (u16*)(ws + WS_WKQV);
  u16* wo_bf = (u16*)(ws + WS_WO);
  u16* outp = (u16*)(ws + WS_OUTP);
  u16* xn_t = (u16*)d_out;   // lower 134MB of d_out used as scratch; dead before k_merge writes

  k_prep  <<<32,   256, 0, stream>>>(Wk, Wq, Wv, Wo, wkqv, wo_bf);
  k_stats1<<<1024, 256, 0, stream>>>(x, part);
  k_stats2<<<1,    128, 0, stream>>>(part, gamma, beta, scale, shift);
  k_norm_t<<<2048, 256, 0, stream>>>(x, scale, shift, xn_t);
  k_attn  <<<8192, 256, 0, stream>>>(xn_t, wkqv, wo_bf, outp);
  k_merge <<<1024, 256, 0, stream>>>(x, outp, out);
}